// Round 5
// baseline (2329.298 us; speedup 1.0000x reference)
//
#include <hip/hip_runtime.h>
#include <hip/hip_bf16.h>
#include <cstdint>
#include <cstddef>

// ---------------------------------------------------------------------------
// RANNet: 2-layer recurrent additive network, B=128 S=2048 D=H=256, fc head.
// Round 7: rec on 128 CUs (64 WGs x 2 batch rows per layer).
//   mega(k) = rec0(chunk k)[blk 0-63] || rec1(chunk k-2)[blk 64-127]
//             || gemm0(k+1)+gemm1(k-1)[blk 128-223]
// Per-CU MFMA issue (256 MFMA/WG/step) is invariant to the batch split, but
// the epilogue scales: each lane now owns ONE h-element -> 3 transcendentals,
// 3 preact dwords, 6 cndmask, 1 LDS write per step (half of round 6).
// preP layout [t][64 wg][768 c][2 r]; GEMM epilogue stores two float2.
// 84 KB LDS pad keeps 1 block/CU so gemm can't co-schedule with rec.
// ---------------------------------------------------------------------------

typedef __bf16 bf16;
typedef __bf16 bf16x8 __attribute__((ext_vector_type(8)));
typedef __bf16 bf16x4 __attribute__((ext_vector_type(4)));
typedef __bf16 bf16x2 __attribute__((ext_vector_type(2)));
typedef float  floatx4 __attribute__((ext_vector_type(4)));

#define B_   128
#define S_   2048
#define H_   256
#define NEG_LOG2E -1.442695040888963f
#define NGB  96                  // gemm worker blocks in mega
#define SMEM_BYTES (84 * 1024)   // > 160KiB/2 -> guarantees 1 block per CU

// ---------------------------------------------------------------------------
// Weight prep: concat + fp32->bf16 ( W*cat rows = [Wf;Wi;Wx], U*cat = [Uf;Ui] )
// fcWT = transpose(fcW) kept fp32 for the epilogue.
// ---------------------------------------------------------------------------
__global__ void prep_weights(
    const float* __restrict__ Wf0, const float* __restrict__ Wi0, const float* __restrict__ Wx0,
    const float* __restrict__ Wf1, const float* __restrict__ Wi1, const float* __restrict__ Wx1,
    const float* __restrict__ Uf0, const float* __restrict__ Ui0,
    const float* __restrict__ Uf1, const float* __restrict__ Ui1,
    const float* __restrict__ bf0, const float* __restrict__ bi0, const float* __restrict__ bx0,
    const float* __restrict__ bf1, const float* __restrict__ bi1, const float* __restrict__ bx1,
    const float* __restrict__ fcW,
    bf16* __restrict__ W0cat, bf16* __restrict__ W1cat,
    bf16* __restrict__ U0cat, bf16* __restrict__ U1cat,
    float* __restrict__ b0cat, float* __restrict__ b1cat, float* __restrict__ fcWT)
{
    int tid = blockIdx.x * blockDim.x + threadIdx.x;
    int nth = gridDim.x * blockDim.x;
    for (int idx = tid; idx < 768 * 256; idx += nth) {
        int r = idx >> 8, k = idx & 255, rr = r & 255;
        const float* s0 = (r < 256) ? Wf0 : ((r < 512) ? Wi0 : Wx0);
        const float* s1 = (r < 256) ? Wf1 : ((r < 512) ? Wi1 : Wx1);
        W0cat[idx] = (bf16)s0[rr * 256 + k];
        W1cat[idx] = (bf16)s1[rr * 256 + k];
    }
    for (int idx = tid; idx < 512 * 256; idx += nth) {
        int r = idx >> 8, k = idx & 255, rr = r & 255;
        U0cat[idx] = (bf16)((r < 256 ? Uf0 : Ui0)[rr * 256 + k]);
        U1cat[idx] = (bf16)((r < 256 ? Uf1 : Ui1)[rr * 256 + k]);
    }
    for (int idx = tid; idx < 768; idx += nth) {
        const float* s0 = (idx < 256) ? bf0 : ((idx < 512) ? bi0 : bx0);
        const float* s1 = (idx < 256) ? bf1 : ((idx < 512) ? bi1 : bx1);
        b0cat[idx] = s0[idx & 255];
        b1cat[idx] = s1[idx & 255];
    }
    for (int idx = tid; idx < 256 * 256; idx += nth) {
        int h = idx >> 8, o = idx & 255;
        fcWT[idx] = fcW[o * 256 + h];   // fcWT[h][o]
    }
}

// ---------------------------------------------------------------------------
// x (fp32, [B][S][D]) -> xa (bf16, [S][B][D])  (full sequence, one launch)
// ---------------------------------------------------------------------------
__global__ void convert_x(const float* __restrict__ x, bf16* __restrict__ xa, int t0, int T)
{
    int tid = blockIdx.x * blockDim.x + threadIdx.x;   // T*128*64 threads
    int d4 = tid & 63;
    int b  = (tid >> 6) & 127;
    int t  = tid >> 13;
    if (t >= T) return;
    const float4* src = (const float4*)(x + ((size_t)b * S_ + t0 + t) * H_) + d4;
    float4 v = *src;
    bf16x4 o = { (bf16)v.x, (bf16)v.y, (bf16)v.z, (bf16)v.w };
    *((bf16x4*)(xa + ((size_t)t * B_ + b) * H_) + d4) = o;
}

// ---------------------------------------------------------------------------
// Device: one 128x128 preact GEMM tile (512 thr, 8 waves, 64x32 per wave).
// C[128 rows][128 of 768 cols] = A[128][256] @ W[768][256]^T + bias, written
// f32 into rec layout preP[(t*64 + (m>>1))*1536 + c*2 + (m&1)];
// f/i (c<512) pre-scaled by -log2(e). Stores are coalesced float2 pairs.
// ---------------------------------------------------------------------------
__device__ __forceinline__ void gemm_tile(
    char* smem,
    const bf16* __restrict__ Abase,   // 128 rows, row stride 256
    const bf16* __restrict__ W, const float* __restrict__ bias,
    float* __restrict__ preP, int t, int nb)
{
    bf16* At = (bf16*)smem;           // [128][32]
    bf16* Bt = (bf16*)smem + 128 * 32;
    int n0 = nb * 128;
    int tid = threadIdx.x;
    int lane = tid & 63, wave = tid >> 6;
    int wm = (wave >> 2) * 64, wn = (wave & 3) * 32;
    int qm = lane & 15, qk = lane >> 4;
    floatx4 acc[4][2] = {};

    for (int k0 = 0; k0 < 256; k0 += 32) {
        {   // stage: 512 threads x one 16B chunk per buffer
            int c = tid, row = c >> 2, kc = c & 3;
            *(bf16x8*)(At + c * 8) = *(const bf16x8*)(Abase + (size_t)row * 256 + k0 + kc * 8);
            *(bf16x8*)(Bt + c * 8) = *(const bf16x8*)(W + (size_t)(n0 + row) * 256 + k0 + kc * 8);
        }
        __syncthreads();
        bf16x8 af[4], bfr[2];
#pragma unroll
        for (int i = 0; i < 4; ++i)
            af[i] = *(const bf16x8*)(At + (wm + i * 16 + qm) * 32 + qk * 8);
#pragma unroll
        for (int n = 0; n < 2; ++n)
            bfr[n] = *(const bf16x8*)(Bt + (wn + n * 16 + qm) * 32 + qk * 8);
#pragma unroll
        for (int mi = 0; mi < 4; ++mi)
#pragma unroll
            for (int ni = 0; ni < 2; ++ni)
                acc[mi][ni] = __builtin_amdgcn_mfma_f32_16x16x32_bf16(af[mi], bfr[ni], acc[mi][ni], 0, 0, 0);
        __syncthreads();
    }
#pragma unroll
    for (int mi = 0; mi < 4; ++mi) {
        int b = wm + mi * 16 + qk * 4;        // rows b..b+3 (b even)
        int wgA = b >> 1;                     // rows b,b+1 ; wgA+1: rows b+2,b+3
#pragma unroll
        for (int ni = 0; ni < 2; ++ni) {
            int c = n0 + wn + ni * 16 + qm;
            int g = c >> 8;
            float bb = bias[c];
            float v0 = acc[mi][ni][0] + bb, v1 = acc[mi][ni][1] + bb;
            float v2 = acc[mi][ni][2] + bb, v3 = acc[mi][ni][3] + bb;
            if (g < 2) {
                v0 *= NEG_LOG2E; v1 *= NEG_LOG2E;
                v2 *= NEG_LOG2E; v3 *= NEG_LOG2E;
            }
            float2 w0 = { v0, v1 }, w1 = { v2, v3 };
            *(float2*)(preP + ((size_t)t * 64 + wgA)     * 1536 + (size_t)c * 2) = w0;
            *(float2*)(preP + ((size_t)t * 64 + wgA + 1) * 1536 + (size_t)c * 2) = w1;
        }
    }
}

// ---------------------------------------------------------------------------
// Device: recurrence for one WG (2 batch rows). 512 thr, 8 waves; wave w owns
// h-cols [32w,32w+32), each lane ONE h-element:
//   row = (lane>>4)&1, col = 32*wave + 16*((lane>>4)>>1) + (lane&15).
// A rows read as (qm&1) -> C rows replicate mod 2 -> lane's z = one cndmask
// pair: select tile by (lane&32), reg by (lane&16).
// One lgkm-only barrier per step; depth-2 prefetch of 3 dwords/lane/step.
// ---------------------------------------------------------------------------
__device__ __forceinline__ void rec_wg(
    char* smem, int wg,
    const float* __restrict__ preP,  // [T][64 wg][768 c][2 r] f32
    bf16* __restrict__ hout,         // [T][128][256] bf16, or nullptr
    const bf16* __restrict__ Ucat,   // [512][256] = [Uf;Ui]
    float* __restrict__ hstate,      // [128][256] in/out
    int T)
{
    bf16* hbb = (bf16*)smem;             // [2 bufs][2 rows * 272], 544B row stride
    const int tid = threadIdx.x, lane = tid & 63, wave = tid >> 6;
    const int qm = lane & 15, qk = lane >> 4;
    const int row = qk & 1;              // batch row this lane owns
    const int ch  = qk >> 1;             // which 16-col half of the wave's 32
    const int cb  = wave * 32;
    const int col = cb + ch * 16 + qm;   // h column this lane owns
    const int bbase = wg * 2;
    const bool selrow = (lane & 16) != 0;
    const bool selch  = (lane & 32) != 0;

    // stationary U fragments (B-operand layout): row n = col index, k contig
    bf16x8 Ufr[2][8], Uir[2][8];
#pragma unroll
    for (int nt = 0; nt < 2; ++nt)
#pragma unroll
        for (int kt = 0; kt < 8; ++kt) {
            Ufr[nt][kt] = *(const bf16x8*)(Ucat + (size_t)(cb + nt * 16 + qm) * 256 + kt * 32 + qk * 8);
            Uir[nt][kt] = *(const bf16x8*)(Ucat + (size_t)(256 + cb + nt * 16 + qm) * 256 + kt * 32 + qk * 8);
        }
    {   // init LDS h (buf 0): 2 rows x 256 cols, 1 col/thread
        int r2 = tid >> 8, c2 = tid & 255;
        hbb[r2 * 272 + c2] = (bf16)hstate[(size_t)(bbase + r2) * 256 + c2];
    }
    float hm = hstate[(size_t)(bbase + row) * 256 + col];
    __syncthreads();

    // per-lane preact: idx = t*98304 + wg*1536 + (g*256 + col)*2 + row
    const float* pw = preP + (size_t)wg * 1536 + (size_t)(col * 2 + row);
#define PLD(dst, tt) { size_t o_ = (size_t)(tt) * 98304;                   \
        dst[0] = pw[o_]; dst[1] = pw[o_ + 512]; dst[2] = pw[o_ + 1024]; }

    int cur = 0;

    // lane's z: tile nt=ch, reg j=row  (C[m][n]: m=qk*4+j -> batch=(j&1))
    auto pick = [&](floatx4 v0, floatx4 v1) -> float {
        float a0 = selrow ? v0[1] : v0[0];
        float a1 = selrow ? v1[1] : v1[0];
        return selch ? a1 : a0;
    };

    auto step = [&](int t, const float* p) {
        floatx4 f0{}, f1{}, i0{}, i1{};
        const bf16* hc = hbb + cur * (2 * 272);
#pragma unroll
        for (int kt = 0; kt < 8; ++kt) {
            bf16x8 a = *(const bf16x8*)(hc + (qm & 1) * 272 + kt * 32 + qk * 8);
            f0 = __builtin_amdgcn_mfma_f32_16x16x32_bf16(a, Ufr[0][kt], f0, 0, 0, 0);
            f1 = __builtin_amdgcn_mfma_f32_16x16x32_bf16(a, Ufr[1][kt], f1, 0, 0, 0);
            i0 = __builtin_amdgcn_mfma_f32_16x16x32_bf16(a, Uir[0][kt], i0, 0, 0, 0);
            i1 = __builtin_amdgcn_mfma_f32_16x16x32_bf16(a, Uir[1][kt], i1, 0, 0, 0);
        }
        float zf = pick(f0, f1), zi = pick(i0, i1);
        bf16* hn = hbb + (cur ^ 1) * (2 * 272);
        // f = sigmoid(zf+xf); i = sigmoid(zi+xi); h = f*h + i*xp
        // = [h*(1+ei) + xp*(1+ef)] / [(1+ef)(1+ei)],  e* = exp2(-K*z)
        float ef = fminf(fmaf(zf, NEG_LOG2E, p[0]), 80.0f);
        float ei = fminf(fmaf(zi, NEG_LOG2E, p[1]), 80.0f);
        float A1 = 1.0f + __builtin_amdgcn_exp2f(ef);
        float B1 = 1.0f + __builtin_amdgcn_exp2f(ei);
        float N  = fmaf(hm, B1, p[2] * A1);
        hm = N * __builtin_amdgcn_rcpf(A1 * B1);
        hn[row * 272 + col] = (bf16)hm;
        // LDS-visibility barrier only; global prefetch stays in flight.
        asm volatile("s_waitcnt lgkmcnt(0)\n\ts_barrier" ::: "memory");
        if (hout) {   // coalesced store of h_t from the just-written buffer
            int r2 = tid >> 8, c2 = tid & 255;
            hout[((size_t)t * 128 + bbase + r2) * 256 + c2] = hn[r2 * 272 + c2];
        }
        cur ^= 1;
    };

    // depth-2 prefetch, 4 statically-named buffers, loop unrolled x4
    float bA[3], bB[3], bC[3], bD[3];
    PLD(bA, 0);
    PLD(bB, 1);
    for (int t = 0; t < T; t += 4) {
        PLD(bC, (t + 2 < T) ? t + 2 : T - 1);
        step(t, bA);
        PLD(bD, (t + 3 < T) ? t + 3 : T - 1);
        step(t + 1, bB);
        PLD(bA, (t + 4 < T) ? t + 4 : T - 1);
        step(t + 2, bC);
        PLD(bB, (t + 5 < T) ? t + 5 : T - 1);
        step(t + 3, bD);
    }
#undef PLD
    hstate[(size_t)(bbase + row) * 256 + col] = hm;
}

// ---------------------------------------------------------------------------
// Mega pipeline tick: blocks 0-63 rec0(chunk k), 64-127 rec1(chunk k-2),
// 128..128+NGB-1 grid-stride over gemm0(chunk k+1) + gemm1(chunk k-1) tiles.
// flags: bit0 rec0, bit1 gemm1, bit2 rec1, bit3 gemm0.
// ---------------------------------------------------------------------------
__global__ __launch_bounds__(512) void mega(
    const bf16* __restrict__ xa, int t0n,
    const bf16* __restrict__ W0, const float* __restrict__ b0,
    const bf16* __restrict__ W1, const float* __restrict__ b1,
    const bf16* __restrict__ U0, const bf16* __restrict__ U1,
    float* __restrict__ h0s, float* __restrict__ h1s,
    float* __restrict__ pre0n,        // gemm0 out  (chunk k+1)
    const float* __restrict__ pre0c,  // rec0  in   (chunk k)
    bf16*  __restrict__ h1bc,         // rec0  out  (chunk k)
    const bf16* __restrict__ h1bp,    // gemm1 in   (chunk k-1)
    float* __restrict__ pre1p,        // gemm1 out  (chunk k-1)
    const float* __restrict__ pre1pp, // rec1  in   (chunk k-2)
    int flags, int T)
{
    __shared__ __align__(16) char smem[SMEM_BYTES];
    int bx = blockIdx.x;
    if (bx < 64) {
        if (flags & 1) rec_wg(smem, bx, pre0c, h1bc, U0, h0s, T);
        return;
    }
    if (bx < 128) {
        if (flags & 4) rec_wg(smem, bx - 64, pre1pp, nullptr, U1, h1s, T);
        return;
    }
    int ng0 = (flags & 8) ? T * 6 : 0;
    int ng1 = (flags & 2) ? T * 6 : 0;
    for (int tile = bx - 128; tile < ng0 + ng1; tile += NGB) {
        bool is0 = tile < ng0;
        int tt = is0 ? tile : tile - ng0;
        int t = tt / 6, nb = tt - t * 6;
        const bf16* A = is0 ? (xa + (size_t)(t0n + t) * 32768)
                            : (h1bp + (size_t)t * 32768);
        gemm_tile(smem, A, is0 ? W0 : W1, is0 ? b0 : b1,
                  is0 ? pre0n : pre1p, t, nb);
    }
}

// ---------------------------------------------------------------------------
// fc head: out[b][o] = fcb[o] + sum_h h2[b][h] * fcWT[h][o]   (all fp32)
// ---------------------------------------------------------------------------
__global__ void fc_head(const float* __restrict__ h2, const float* __restrict__ fcWT,
                        const float* __restrict__ fcb, float* __restrict__ out)
{
    int b = blockIdx.x, o = threadIdx.x;
    __shared__ float hrow[256];
    hrow[o] = h2[(size_t)b * 256 + o];
    __syncthreads();
    float acc = fcb[o];
#pragma unroll 8
    for (int h = 0; h < 256; ++h)
        acc = fmaf(hrow[h], fcWT[h * 256 + o], acc);
    out[(size_t)b * 256 + o] = acc;
}

// ---------------------------------------------------------------------------
extern "C" void kernel_launch(void* const* d_in, const int* in_sizes, int n_in,
                              void* d_out, int out_size, void* d_ws, size_t ws_size,
                              hipStream_t stream)
{
    (void)in_sizes; (void)n_in; (void)out_size;
    const float* x   = (const float*)d_in[0];
    const float* Wf0 = (const float*)d_in[1];
    const float* bf0 = (const float*)d_in[2];
    const float* Uf0 = (const float*)d_in[3];
    const float* Wi0 = (const float*)d_in[4];
    const float* bi0 = (const float*)d_in[5];
    const float* Ui0 = (const float*)d_in[6];
    const float* Wx0 = (const float*)d_in[7];
    const float* bx0 = (const float*)d_in[8];
    const float* Wf1 = (const float*)d_in[9];
    const float* bf1 = (const float*)d_in[10];
    const float* Uf1 = (const float*)d_in[11];
    const float* Wi1 = (const float*)d_in[12];
    const float* bi1 = (const float*)d_in[13];
    const float* Ui1 = (const float*)d_in[14];
    const float* Wx1 = (const float*)d_in[15];
    const float* bx1 = (const float*)d_in[16];
    const float* fcW = (const float*)d_in[17];
    const float* fcb = (const float*)d_in[18];

    char* p = (char*)d_ws;
    auto alloc = [&](size_t bytes) -> char* {
        char* r = p; p += (bytes + 255) & ~(size_t)255; return r;
    };
    bf16*  W0cat = (bf16*)alloc(768 * 256 * 2);
    bf16*  W1cat = (bf16*)alloc(768 * 256 * 2);
    bf16*  U0cat = (bf16*)alloc(512 * 256 * 2);
    bf16*  U1cat = (bf16*)alloc(512 * 256 * 2);
    float* b0cat = (float*)alloc(768 * 4);
    float* b1cat = (float*)alloc(768 * 4);
    float* fcWT  = (float*)alloc(256 * 256 * 4);
    float* h0s   = (float*)alloc(128 * 256 * 4);
    float* h1s   = (float*)alloc(128 * 256 * 4);
    size_t fixed = (size_t)(p - (char*)d_ws);

    // need(T_c) = fixed + xa(full S) + 2*pre0 + 2*pre1 + 2*h1b
    int T_c = 128;
    while (T_c > 32 &&
           fixed + 134217728ULL + (size_t)T_c * 1703936ULL + 4096 > ws_size)
        T_c >>= 1;
    bf16*  xa    = (bf16*)alloc((size_t)S_ * 128 * 256 * 2);
    float* pre0s[2], *pre1s[2];
    bf16*  h1bs[2];
    pre0s[0] = (float*)alloc((size_t)T_c * 128 * 768 * 4);
    pre0s[1] = (float*)alloc((size_t)T_c * 128 * 768 * 4);
    pre1s[0] = (float*)alloc((size_t)T_c * 128 * 768 * 4);
    pre1s[1] = (float*)alloc((size_t)T_c * 128 * 768 * 4);
    h1bs[0]  = (bf16*)alloc((size_t)T_c * 128 * 256 * 2);
    h1bs[1]  = (bf16*)alloc((size_t)T_c * 128 * 256 * 2);

    hipMemsetAsync(h0s, 0, 128 * 256 * 4, stream);
    hipMemsetAsync(h1s, 0, 128 * 256 * 4, stream);

    prep_weights<<<512, 256, 0, stream>>>(Wf0, Wi0, Wx0, Wf1, Wi1, Wx1,
                                          Uf0, Ui0, Uf1, Ui1,
                                          bf0, bi0, bx0, bf1, bi1, bx1, fcW,
                                          W0cat, W1cat, U0cat, U1cat, b0cat, b1cat, fcWT);
    convert_x<<<S_ * 32, 256, 0, stream>>>(x, xa, 0, S_);

    int NC = S_ / T_c;
    for (int k = -1; k <= NC + 1; ++k) {
        int flags = 0;
        if (k >= 0 && k < NC)     flags |= 1;   // rec0 chunk k
        if (k >= 1 && k <= NC)    flags |= 2;   // gemm1 chunk k-1
        if (k >= 2 && k <= NC+1)  flags |= 4;   // rec1 chunk k-2
        if (k <= NC - 2)          flags |= 8;   // gemm0 chunk k+1
        mega<<<128 + NGB, 512, 0, stream>>>(
            xa, (k + 1) * T_c,
            W0cat, b0cat, W1cat, b1cat, U0cat, U1cat, h0s, h1s,
            pre0s[(k + 1) & 1],   // gemm0 out
            pre0s[k & 1],         // rec0 in
            h1bs[k & 1],          // rec0 out
            h1bs[(k - 1) & 1],    // gemm1 in
            pre1s[(k - 1) & 1],   // gemm1 out
            pre1s[k & 1],         // rec1 in  ((k-2)&1 == k&1)
            flags, T_c);
    }
    fc_head<<<128, 256, 0, stream>>>(h1s, fcWT, fcb, (float*)d_out);
}